// Round 8
// baseline (1026.056 us; speedup 1.0000x reference)
//
#include <hip/hip_runtime.h>

typedef __bf16 bf16_t;
typedef __bf16 bf16x4 __attribute__((ext_vector_type(4)));
typedef __bf16 bf16x8 __attribute__((ext_vector_type(8)));
typedef float  f32x4  __attribute__((ext_vector_type(4)));

#define HID    128
#define DIO    80
#define G4     512
#define TSTEP  512
#define BB     16
#define NBATCH 4096
#define NBLK   (NBATCH / BB)
#define HSTR   136  // LDS row stride (bf16 elems)

// Activation-domain scaling folded into the weights (preprocessing):
//   i,f,o rows scaled by -log2(e)  -> exp2(acc) = e^{-gate}
//   g rows scaled by +2*log2(e)    -> exp2(acc) = e^{2g}
// c state kept in the 2*log2(e)-scaled domain so tanh(c) = (exp2(c')-1)/(exp2(c')+1).
#define NL2E  -1.4426950408889634f
#define P2L2E  2.8853900817779268f

// Fragment layout (identical indexing for A- and B-operand of 16x16x32 bf16):
// frag tile (ntile,kt): elem[lane*8+j] = W[n=ntile*16+(lane&15)][k=kt*32+(lane>>4)*8+j]
__device__ bf16_t g_weff_frags[128 * 512];
__device__ bf16_t g_whh_frags[128 * 512];
__device__ bf16_t g_wfc_frags[20 * 512];
__device__ float  g_weff[G4 * HID];
__device__ float  g_beff[G4];
__device__ float  g_b1[G4];

// W_eff = W_hh + W_ih @ W_fc ; b_eff = b_ih + b_hh + W_ih @ b_fc ; b1 = b_ih + b_hh
__global__ void k_weff(const float* __restrict__ W_ih, const float* __restrict__ W_hh,
                       const float* __restrict__ b_ih, const float* __restrict__ b_hh,
                       const float* __restrict__ W_fc, const float* __restrict__ b_fc) {
  int gid = blockIdx.x * blockDim.x + threadIdx.x;
  int g = gid >> 7, k = gid & 127;
  float sc = ((g >> 7) == 2) ? P2L2E : NL2E;  // gate order i,f,g,o; g-gate rows = [256,384)
  float acc = W_hh[g * HID + k];
#pragma unroll 8
  for (int d = 0; d < DIO; ++d)
    acc = fmaf(W_ih[g * DIO + d], W_fc[d * HID + k], acc);
  g_weff[g * HID + k] = acc * sc;
  if (k == 0) {
    float bb = b_ih[g] + b_hh[g];
    g_b1[g] = bb * sc;
    float be = bb;
    for (int d = 0; d < DIO; ++d) be = fmaf(W_ih[g * DIO + d], b_fc[d], be);
    g_beff[g] = be * sc;
  }
}

__global__ void k_frag(const float* __restrict__ W_hh, const float* __restrict__ W_fc) {
  int tile = blockIdx.x;  // 0..275
  int lane = threadIdx.x;
  int c = lane & 15, q = lane >> 4;
  if (tile < 128) {
    int gtile = tile >> 2, kt = tile & 3;
    int n = gtile * 16 + c;
#pragma unroll
    for (int j = 0; j < 8; ++j)
      g_weff_frags[tile * 512 + lane * 8 + j] = (bf16_t)g_weff[n * HID + kt * 32 + q * 8 + j];
  } else if (tile < 256) {
    int t2 = tile - 128;
    int gtile = t2 >> 2, kt = t2 & 3;
    int n = gtile * 16 + c;
    float sc = ((n >> 7) == 2) ? P2L2E : NL2E;
#pragma unroll
    for (int j = 0; j < 8; ++j)
      g_whh_frags[t2 * 512 + lane * 8 + j] = (bf16_t)(W_hh[n * HID + kt * 32 + q * 8 + j] * sc);
  } else {
    int t2 = tile - 256;  // 0..19 (W_fc unscaled: y output path)
    int yt = t2 >> 2, kt = t2 & 3;
    int n = yt * 16 + c;
#pragma unroll
    for (int j = 0; j < 8; ++j)
      g_wfc_frags[t2 * 512 + lane * 8 + j] = (bf16_t)W_fc[n * HID + kt * 32 + q * 8 + j];
  }
}

__device__ __forceinline__ float fexp2(float x) { return __builtin_amdgcn_exp2f(x); }
__device__ __forceinline__ float frcp(float x)  { return __builtin_amdgcn_rcpf(x); }

#define MFMA16(A, B, C) __builtin_amdgcn_mfma_f32_16x16x32_bf16((A), (B), (C), 0, 0, 0)

// Pointwise tail for one r (identical DAG to prior rounds).
#define TAILR(ACC, CST, HV, R)                                                         \
  do {                                                                                 \
    float Eg = fexp2(ACC[2][R]); /* e^2g */                                            \
    float ag = 1.0f + Eg;                                                              \
    float Ei = fexp2(ACC[0][R]); /* e^-i */                                            \
    float ai = 1.0f + Ei;                                                              \
    float Ef = fexp2(ACC[1][R]); /* e^-f */                                            \
    float af = 1.0f + Ef;                                                              \
    float P1 = ai * ag;                                                                \
    float Rr = frcp(P1 * af);                                                          \
    float tg = __builtin_fmaf(Eg, P2L2E, -P2L2E); /* 2L*(Eg-1) */                      \
    float m2 = tg * af;                                                                \
    float u  = __builtin_fmaf(P1, CST[R], m2);                                         \
    float cn = u * Rr; /* = sig(f)*c + 2L*sig(i)*tanh(g) */                            \
    CST[R] = cn;                                                                       \
    float cc = fminf(cn, 80.0f); /* exp2 overflow guard */                             \
    float Ec = fexp2(cc);        /* e^2c */                                            \
    float Eo = fexp2(ACC[3][R]); /* e^-o */                                            \
    float R2 = frcp((1.0f + Eo) * (1.0f + Ec));                                        \
    HV[R] = (bf16_t)((Ec - 1.0f) * R2); /* sig(o)*tanh(c) */                           \
  } while (0)

#define GKT_FIRST(K, SRC)                                                              \
  acc[0] = MFMA16(Wg[0][K], SRC, bias[0]); acc[1] = MFMA16(Wg[1][K], SRC, bias[1]);    \
  acc[2] = MFMA16(Wg[2][K], SRC, bias[2]); acc[3] = MFMA16(Wg[3][K], SRC, bias[3]);
#define GKT(K, SRC)                                                                    \
  acc[0] = MFMA16(Wg[0][K], SRC, acc[0]); acc[1] = MFMA16(Wg[1][K], SRC, acc[1]);      \
  acc[2] = MFMA16(Wg[2][K], SRC, acc[2]); acc[3] = MFMA16(Wg[3][K], SRC, acc[3]);

#define YEMIT(PRV)                                                                     \
  { f32x4 ya = MFMA16(Wy[0], PRV[0], ybias); ya = MFMA16(Wy[1], PRV[1], ya);           \
    ya = MFMA16(Wy[2], PRV[2], ya); ya = MFMA16(Wy[3], PRV[3], ya);                    \
    *(f32x4*)outp = ya; outp += DIO; }

// Spin until min(flags[base..base+3]) >= need. Volatile reads (re-issued each iter);
// sched_barrier keeps later LDS data reads from being scheduled above the loop.
__device__ __forceinline__ void poll_ge(volatile unsigned* vf, int base, unsigned need) {
  for (;;) {
    unsigned a = vf[base + 0], b = vf[base + 1], x = vf[base + 2], d = vf[base + 3];
    unsigned m0 = a < b ? a : b, m1 = x < d ? x : d;
    if ((m0 < m1 ? m0 : m1) >= need) break;
  }
  __builtin_amdgcn_sched_barrier(0);
}

// 256 blocks x 512 threads (8 waves, 2/SIMD). Block owns 16 batch rows for 512 steps.
// BARRIER-FREE RECURRENCE: per-wave LDS flags (flag_w = t+1 <=> wave w wrote its h(t)
// slice, set after lgkmcnt(0)). A wave waits only AT THE CONSUMING MFMA: flags 0-3
// (h_low) before kt01, flags 4-7 (h_high) before kt23. HIGH waves consume kt23 first
// (own half -> no wait), LOW waves kt01 first. Wave phases float (+-~1/4 step) instead
// of barrier-locking -> the 2 waves/SIMD settle at opposite phases (trans contention
// pushes them apart) and one wave's tail overlaps the other's MFMAs (m114 regime).
// Overwrite safety: wave writes h(t) only after its polls >= t certify all waves wrote
// h(t-1), hence finished reading h(t-2) = the buffer being overwritten. No deadlock:
// flags monotone, dependency DAG acyclic, no collective wait point.
__global__ __launch_bounds__(512, 2) void k_lstm(const float* __restrict__ h0,
                                                 const float* __restrict__ b_fc,
                                                 float* __restrict__ out) {
  __shared__ __align__(16) bf16_t hbuf[2][BB * HSTR];
  __shared__ unsigned hflags[8];
  volatile unsigned* vf = hflags;
  const int tid = threadIdx.x;
  const int lane = tid & 63;
  const int w = tid >> 6;  // 0..7
  const int c = lane & 15, q = lane >> 4;
  const int b0 = blockIdx.x * BB;
  const bool isHigh = (w >= 4);

  // stage h0 -> hbuf[0]
  for (int i = tid; i < BB * HID; i += 512) {
    int r = i >> 7, k = i & 127;
    hbuf[0][r * HSTR + k] = (bf16_t)h0[(long)(b0 + r) * HID + k];
  }
  if (lane == 0) hflags[w] = 1;  // flag=1 <=> h(0) ready (valid after the one barrier)

  // W_fc A-fragments: waves 0..4 own y-tile w (dio cols w*16..w*16+16)
  bf16x8 Wy[4];
  f32x4  ybias;
  if (w < 5) {
#pragma unroll
    for (int kt = 0; kt < 4; ++kt)
      Wy[kt] = *(const bf16x8*)&g_wfc_frags[(w * 4 + kt) * 512 + lane * 8];
#pragma unroll
    for (int r = 0; r < 4; ++r) ybias[r] = b_fc[w * 16 + q * 4 + r];
  }

  bf16x8 Wg[4][4];  // [gate][ktile] — register-resident; wave w owns unit-tile w
  f32x4  bias[4];
  auto load_wg = [&](const bf16_t* frags, const float* bsrc) {
#pragma unroll
    for (int G = 0; G < 4; ++G) {
      int gtile = G * 8 + w;
#pragma unroll
      for (int r = 0; r < 4; ++r) bias[G][r] = bsrc[gtile * 16 + q * 4 + r];
#pragma unroll
      for (int kt = 0; kt < 4; ++kt)
        Wg[G][kt] = *(const bf16x8*)&frags[(gtile * 4 + kt) * 512 + lane * 8];
    }
  };

  f32x4 cst = (f32x4){0, 0, 0, 0};  // c state (2*log2e-scaled), batch row c
  bf16x8 hfA[4], hfB[4];            // ping-pong h fragments (RD = h(t-1), PR = h(t-2))

  load_wg(g_whh_frags, g_b1);
  __syncthreads();  // ONLY barrier: h0 staged + flags initialized

  float* outp = out + (long)(b0 + c) * TSTEP * DIO + w * 16 + q * 4;  // row 0

  // ---------- iter 1: gates = h0 @ W_hh^T + b1 (x0 == 0); no y ----------
#pragma unroll
  for (int kt = 0; kt < 4; ++kt)
    hfA[kt] = *(const bf16x8*)&hbuf[0][c * HSTR + kt * 32 + q * 8];
  {
    f32x4 acc[4];
    GKT_FIRST(0, hfA[0]); GKT(1, hfA[1]); GKT(2, hfA[2]); GKT(3, hfA[3]);
    bf16x4 hv;
    TAILR(acc, cst, hv, 0); TAILR(acc, cst, hv, 1);
    TAILR(acc, cst, hv, 2); TAILR(acc, cst, hv, 3);
    *(bf16x4*)&hbuf[1][c * HSTR + w * 16 + q * 4] = hv;  // h(1)
    asm volatile("s_waitcnt lgkmcnt(0)" ::: "memory");
    if (lane == 0) vf[w] = 2;
  }
  load_wg(g_weff_frags, g_beff);  // switch to fused recurrence weights

// Iteration T (T>=2): reads h(T-1) -> RD (with point-of-use polls), computes gates+tail,
// writes h(T), sets flag=T+1. EMIT: y(h(T-2)) from PR, placed to cover the 2nd read pair.
#define ITER(RD, PR, T, EMIT)                                                          \
  do {                                                                                 \
    const int rb = ((T)-1) & 1, wb = (T)&1;                                            \
    f32x4 acc[4];                                                                      \
    if (!isHigh) {                                                                     \
      poll_ge(vf, 0, (unsigned)(T));                                                   \
      RD[0] = *(const bf16x8*)&hbuf[rb][c * HSTR + 0 * 32 + q * 8];                    \
      RD[1] = *(const bf16x8*)&hbuf[rb][c * HSTR + 1 * 32 + q * 8];                    \
      GKT_FIRST(0, RD[0]); GKT(1, RD[1]);                                              \
      poll_ge(vf, 4, (unsigned)(T));                                                   \
      RD[2] = *(const bf16x8*)&hbuf[rb][c * HSTR + 2 * 32 + q * 8];                    \
      RD[3] = *(const bf16x8*)&hbuf[rb][c * HSTR + 3 * 32 + q * 8];                    \
      if ((EMIT) && w < 5) YEMIT(PR);                                                  \
      GKT(2, RD[2]); GKT(3, RD[3]);                                                    \
    } else {                                                                           \
      poll_ge(vf, 4, (unsigned)(T));                                                   \
      RD[2] = *(const bf16x8*)&hbuf[rb][c * HSTR + 2 * 32 + q * 8];                    \
      RD[3] = *(const bf16x8*)&hbuf[rb][c * HSTR + 3 * 32 + q * 8];                    \
      GKT_FIRST(2, RD[2]); GKT(3, RD[3]);                                              \
      poll_ge(vf, 0, (unsigned)(T));                                                   \
      RD[0] = *(const bf16x8*)&hbuf[rb][c * HSTR + 0 * 32 + q * 8];                    \
      RD[1] = *(const bf16x8*)&hbuf[rb][c * HSTR + 1 * 32 + q * 8];                    \
      if ((EMIT) && w < 5) YEMIT(PR);                                                  \
      GKT(0, RD[0]); GKT(1, RD[1]);                                                    \
    }                                                                                  \
    bf16x4 hv;                                                                         \
    TAILR(acc, cst, hv, 0); TAILR(acc, cst, hv, 1);                                    \
    TAILR(acc, cst, hv, 2); TAILR(acc, cst, hv, 3);                                    \
    *(bf16x4*)&hbuf[wb][c * HSTR + w * 16 + q * 4] = hv; /* h(T) */                    \
    asm volatile("s_waitcnt lgkmcnt(0)" ::: "memory");                                 \
    if (lane == 0) vf[w] = (unsigned)((T) + 1);                                        \
  } while (0)

  // iter 2 (no y yet: first output row is y(h(1)) at iter 3)
  ITER(hfB, hfA, 2, false);
  // iters 3..512: emit y(h(T-2)) -> rows 0..509
  for (int p = 0; p < 255; ++p) {
    ITER(hfA, hfB, 3 + 2 * p, true);
    ITER(hfB, hfA, 4 + 2 * p, true);
  }

  // epilogue: y(h(511)) from hfB (row 510); then read h(512) and emit (row 511)
  if (w < 5) {
    YEMIT(hfB);
    poll_ge(vf, 0, 513u);
    poll_ge(vf, 4, 513u);
#pragma unroll
    for (int kt = 0; kt < 4; ++kt)
      hfA[kt] = *(const bf16x8*)&hbuf[0][c * HSTR + kt * 32 + q * 8];
    f32x4 ya = MFMA16(Wy[0], hfA[0], ybias);
    ya = MFMA16(Wy[1], hfA[1], ya);
    ya = MFMA16(Wy[2], hfA[2], ya);
    ya = MFMA16(Wy[3], hfA[3], ya);
    *(f32x4*)outp = ya;
  }
#undef ITER
}

extern "C" void kernel_launch(void* const* d_in, const int* in_sizes, int n_in,
                              void* d_out, int out_size, void* d_ws, size_t ws_size,
                              hipStream_t stream) {
  const float* h0   = (const float*)d_in[0];
  const float* W_ih = (const float*)d_in[1];
  const float* W_hh = (const float*)d_in[2];
  const float* b_ih = (const float*)d_in[3];
  const float* b_hh = (const float*)d_in[4];
  const float* W_fc = (const float*)d_in[5];
  const float* b_fc = (const float*)d_in[6];
  float* out = (float*)d_out;

  k_weff<<<256, 256, 0, stream>>>(W_ih, W_hh, b_ih, b_hh, W_fc, b_fc);
  k_frag<<<276, 64, 0, stream>>>(W_hh, W_fc);
  k_lstm<<<NBLK, 512, 0, stream>>>(h0, b_fc, out);
}

// Round 9
// 1023.196 us; speedup vs baseline: 1.0028x; 1.0028x over previous
//
#include <hip/hip_runtime.h>

typedef __bf16 bf16_t;
typedef __bf16 bf16x4 __attribute__((ext_vector_type(4)));
typedef __bf16 bf16x8 __attribute__((ext_vector_type(8)));
typedef float  f32x4  __attribute__((ext_vector_type(4)));

#define HID    128
#define DIO    80
#define G4     512
#define TSTEP  512
#define BB     16
#define NBATCH 4096
#define NBLK   (NBATCH / BB)
#define HSTR   136  // LDS row stride (bf16 elems)

// Activation-domain scaling folded into the weights (preprocessing):
//   i,f,o rows scaled by -log2(e)  -> exp2(acc) = e^{-gate}
//   g rows scaled by +2*log2(e)    -> exp2(acc) = e^{2g}
// c state kept in the 2*log2(e)-scaled domain so tanh(c) = (exp2(c')-1)/(exp2(c')+1).
#define NL2E  -1.4426950408889634f
#define P2L2E  2.8853900817779268f

// Fragment layout (identical indexing for A- and B-operand of 16x16x32 bf16):
// frag tile (ntile,kt): elem[lane*8+j] = W[n=ntile*16+(lane&15)][k=kt*32+(lane>>4)*8+j]
__device__ bf16_t g_weff_frags[128 * 512];
__device__ bf16_t g_whh_frags[128 * 512];
__device__ bf16_t g_wfc_frags[20 * 512];
__device__ float  g_weff[G4 * HID];
__device__ float  g_beff[G4];
__device__ float  g_b1[G4];

// W_eff = W_hh + W_ih @ W_fc ; b_eff = b_ih + b_hh + W_ih @ b_fc ; b1 = b_ih + b_hh
__global__ void k_weff(const float* __restrict__ W_ih, const float* __restrict__ W_hh,
                       const float* __restrict__ b_ih, const float* __restrict__ b_hh,
                       const float* __restrict__ W_fc, const float* __restrict__ b_fc) {
  int gid = blockIdx.x * blockDim.x + threadIdx.x;
  int g = gid >> 7, k = gid & 127;
  float sc = ((g >> 7) == 2) ? P2L2E : NL2E;  // gate order i,f,g,o; g-gate rows = [256,384)
  float acc = W_hh[g * HID + k];
#pragma unroll 8
  for (int d = 0; d < DIO; ++d)
    acc = fmaf(W_ih[g * DIO + d], W_fc[d * HID + k], acc);
  g_weff[g * HID + k] = acc * sc;
  if (k == 0) {
    float bb = b_ih[g] + b_hh[g];
    g_b1[g] = bb * sc;
    float be = bb;
    for (int d = 0; d < DIO; ++d) be = fmaf(W_ih[g * DIO + d], b_fc[d], be);
    g_beff[g] = be * sc;
  }
}

__global__ void k_frag(const float* __restrict__ W_hh, const float* __restrict__ W_fc) {
  int tile = blockIdx.x;  // 0..275
  int lane = threadIdx.x;
  int c = lane & 15, q = lane >> 4;
  if (tile < 128) {
    int gtile = tile >> 2, kt = tile & 3;
    int n = gtile * 16 + c;
#pragma unroll
    for (int j = 0; j < 8; ++j)
      g_weff_frags[tile * 512 + lane * 8 + j] = (bf16_t)g_weff[n * HID + kt * 32 + q * 8 + j];
  } else if (tile < 256) {
    int t2 = tile - 128;
    int gtile = t2 >> 2, kt = t2 & 3;
    int n = gtile * 16 + c;
    float sc = ((n >> 7) == 2) ? P2L2E : NL2E;
#pragma unroll
    for (int j = 0; j < 8; ++j)
      g_whh_frags[t2 * 512 + lane * 8 + j] = (bf16_t)(W_hh[n * HID + kt * 32 + q * 8 + j] * sc);
  } else {
    int t2 = tile - 256;  // 0..19 (W_fc unscaled: y output path)
    int yt = t2 >> 2, kt = t2 & 3;
    int n = yt * 16 + c;
#pragma unroll
    for (int j = 0; j < 8; ++j)
      g_wfc_frags[t2 * 512 + lane * 8 + j] = (bf16_t)W_fc[n * HID + kt * 32 + q * 8 + j];
  }
}

__device__ __forceinline__ float fexp2(float x) { return __builtin_amdgcn_exp2f(x); }
__device__ __forceinline__ float frcp(float x)  { return __builtin_amdgcn_rcpf(x); }

#define MFMA16(A, B, C) __builtin_amdgcn_mfma_f32_16x16x32_bf16((A), (B), (C), 0, 0, 0)

// Pointwise tail for one r (identical DAG to prior rounds).
#define TAILR(ACC, CST, HV, R)                                                         \
  do {                                                                                 \
    float Eg = fexp2(ACC[2][R]); /* e^2g */                                            \
    float ag = 1.0f + Eg;                                                              \
    float Ei = fexp2(ACC[0][R]); /* e^-i */                                            \
    float ai = 1.0f + Ei;                                                              \
    float Ef = fexp2(ACC[1][R]); /* e^-f */                                            \
    float af = 1.0f + Ef;                                                              \
    float P1 = ai * ag;                                                                \
    float Rr = frcp(P1 * af);                                                          \
    float tg = __builtin_fmaf(Eg, P2L2E, -P2L2E); /* 2L*(Eg-1) */                      \
    float m2 = tg * af;                                                                \
    float u  = __builtin_fmaf(P1, CST[R], m2);                                         \
    float cn = u * Rr; /* = sig(f)*c + 2L*sig(i)*tanh(g) */                            \
    CST[R] = cn;                                                                       \
    float cc = fminf(cn, 80.0f); /* exp2 overflow guard */                             \
    float Ec = fexp2(cc);        /* e^2c */                                            \
    float Eo = fexp2(ACC[3][R]); /* e^-o */                                            \
    float R2 = frcp((1.0f + Eo) * (1.0f + Ec));                                        \
    HV[R] = (bf16_t)((Ec - 1.0f) * R2); /* sig(o)*tanh(c) */                           \
  } while (0)

#define GKT_FIRST(K, SRC)                                                              \
  acc[0] = MFMA16(Wg[0][K], SRC, bias[0]); acc[1] = MFMA16(Wg[1][K], SRC, bias[1]);    \
  acc[2] = MFMA16(Wg[2][K], SRC, bias[2]); acc[3] = MFMA16(Wg[3][K], SRC, bias[3]);
#define GKT(K, SRC)                                                                    \
  acc[0] = MFMA16(Wg[0][K], SRC, acc[0]); acc[1] = MFMA16(Wg[1][K], SRC, acc[1]);      \
  acc[2] = MFMA16(Wg[2][K], SRC, acc[2]); acc[3] = MFMA16(Wg[3][K], SRC, acc[3]);

#define YEMIT(PRV)                                                                     \
  { f32x4 ya = MFMA16(Wy[0], PRV[0], ybias); ya = MFMA16(Wy[1], PRV[1], ya);           \
    ya = MFMA16(Wy[2], PRV[2], ya); ya = MFMA16(Wy[3], PRV[3], ya);                    \
    *(f32x4*)outp = ya; outp += DIO; }

// Poll pair-word K (two u16 flags packed in one dword): both halves >= NEED.
// Fast path: 1 volatile LDS dword read + 2 cmps. Slow path: s_sleep spin (no LDS hammer).
#define POLLP(K, NEED)                                                                 \
  do {                                                                                 \
    unsigned _pw = vfp[K];                                                             \
    if ((_pw & 0xFFFFu) < (unsigned)(NEED) || (_pw >> 16) < (unsigned)(NEED)) {        \
      do { __builtin_amdgcn_s_sleep(1); _pw = vfp[K]; }                                \
      while ((_pw & 0xFFFFu) < (unsigned)(NEED) || (_pw >> 16) < (unsigned)(NEED));    \
    }                                                                                  \
    __builtin_amdgcn_sched_barrier(0);                                                 \
  } while (0)

// 256 blocks x 512 threads (8 waves, 2/SIMD). Block owns 16 batch rows for 512 steps.
// PAIR-GRAIN ROTATED SYNC (no barrier in the loop): fragment k of h is produced by
// exactly waves 2k,2k+1; their u16 flags share one dword -> poll = 1 LDS read. Wave w
// reads fragments in rotated order starting at its OWN pair (k0=w>>1, partner-only
// wait ~0), polling each pair at point of use. SIMD-mates (w,w+4) have k0 offset 2 ->
// opposite read orders -> phases can slide; asymmetric setprio (w<4) biases the slide
// to a stable stagger (one mate's trans-tail under the other's MFMA burst).
// Write-safety FREE: the 4 read-polls at step T certify all 8 flags >= T, which is
// exactly the overwrite condition for h(T-2). Flags monotone -> no deadlock.
__global__ __launch_bounds__(512, 2) void k_lstm(const float* __restrict__ h0,
                                                 const float* __restrict__ b_fc,
                                                 float* __restrict__ out) {
  __shared__ __align__(16) bf16_t hbuf[2][BB * HSTR];
  __shared__ __align__(4) unsigned short hfl[8];
  volatile unsigned* vfp = (volatile unsigned*)hfl;  // 4 pair-words
  const int tid = threadIdx.x;
  const int lane = tid & 63;
  const int w = tid >> 6;  // 0..7
  const int c = lane & 15, q = lane >> 4;
  const int b0 = blockIdx.x * BB;

  // stage h0 -> hbuf[0]
  for (int i = tid; i < BB * HID; i += 512) {
    int r = i >> 7, k = i & 127;
    hbuf[0][r * HSTR + k] = (bf16_t)h0[(long)(b0 + r) * HID + k];
  }
  if (tid < 8) hfl[tid] = 1;  // flag=1 <=> h(0) ready (valid after the one barrier)

  // W_fc A-fragments: waves 0..4 own y-tile w (dio cols w*16..w*16+16)
  bf16x8 Wy[4];
  f32x4  ybias;
  if (w < 5) {
#pragma unroll
    for (int kt = 0; kt < 4; ++kt)
      Wy[kt] = *(const bf16x8*)&g_wfc_frags[(w * 4 + kt) * 512 + lane * 8];
#pragma unroll
    for (int r = 0; r < 4; ++r) ybias[r] = b_fc[w * 16 + q * 4 + r];
  }

  bf16x8 Wg[4][4];  // [gate][ktile] — register-resident; wave w owns unit-tile w
  f32x4  bias[4];
  auto load_wg = [&](const bf16_t* frags, const float* bsrc) {
#pragma unroll
    for (int G = 0; G < 4; ++G) {
      int gtile = G * 8 + w;
#pragma unroll
      for (int r = 0; r < 4; ++r) bias[G][r] = bsrc[gtile * 16 + q * 4 + r];
#pragma unroll
      for (int kt = 0; kt < 4; ++kt)
        Wg[G][kt] = *(const bf16x8*)&frags[(gtile * 4 + kt) * 512 + lane * 8];
    }
  };

  f32x4 cst = (f32x4){0, 0, 0, 0};  // c state (2*log2e-scaled), batch row c
  bf16x8 hfA[4], hfB[4];            // ping-pong h fragments (RD = h(t-1), PR = h(t-2))

  load_wg(g_whh_frags, g_b1);
  __syncthreads();  // ONLY barrier: h0 staged + flags initialized

  // asymmetric persistent priority between SIMD-mates (w and w+4 share a SIMD):
  // biases the free-floating phases toward a stable stagger.
  if (w < 4) __builtin_amdgcn_s_setprio(1);

  float* outp = out + (long)(b0 + c) * TSTEP * DIO + w * 16 + q * 4;  // row 0

  // ---------- iter 1: gates = h0 @ W_hh^T + b1 (x0 == 0); no y ----------
#pragma unroll
  for (int kt = 0; kt < 4; ++kt)
    hfA[kt] = *(const bf16x8*)&hbuf[0][c * HSTR + kt * 32 + q * 8];
  {
    f32x4 acc[4];
    GKT_FIRST(0, hfA[0]); GKT(1, hfA[1]); GKT(2, hfA[2]); GKT(3, hfA[3]);
    bf16x4 hv;
    TAILR(acc, cst, hv, 0); TAILR(acc, cst, hv, 1);
    TAILR(acc, cst, hv, 2); TAILR(acc, cst, hv, 3);
    *(bf16x4*)&hbuf[1][c * HSTR + w * 16 + q * 4] = hv;  // h(1)
    asm volatile("s_waitcnt lgkmcnt(0)" ::: "memory");
    if (lane == 0) ((volatile unsigned short*)hfl)[w] = 2;
  }
  load_wg(g_weff_frags, g_beff);  // switch to fused recurrence weights

// Iteration T (T>=2), fragment order KA,KB,KC,KD (literal): poll pair, read, MFMA per
// fragment; y(h(T-2)) from PR after 3rd fragment; tail; write h(T); flag=T+1.
#define ITER_K(RD, PR, T, EMIT, KA, KB, KC, KD)                                        \
  do {                                                                                 \
    const int rb = ((T)-1) & 1, wb = (T)&1;                                            \
    f32x4 acc[4];                                                                      \
    POLLP(KA, (T));                                                                    \
    RD[KA] = *(const bf16x8*)&hbuf[rb][c * HSTR + (KA) * 32 + q * 8];                  \
    GKT_FIRST(KA, RD[KA]);                                                             \
    POLLP(KB, (T));                                                                    \
    RD[KB] = *(const bf16x8*)&hbuf[rb][c * HSTR + (KB) * 32 + q * 8];                  \
    GKT(KB, RD[KB]);                                                                   \
    POLLP(KC, (T));                                                                    \
    RD[KC] = *(const bf16x8*)&hbuf[rb][c * HSTR + (KC) * 32 + q * 8];                  \
    GKT(KC, RD[KC]);                                                                   \
    if ((EMIT) && w < 5) YEMIT(PR);                                                    \
    POLLP(KD, (T));                                                                    \
    RD[KD] = *(const bf16x8*)&hbuf[rb][c * HSTR + (KD) * 32 + q * 8];                  \
    GKT(KD, RD[KD]);                                                                   \
    bf16x4 hv;                                                                         \
    TAILR(acc, cst, hv, 0); TAILR(acc, cst, hv, 1);                                    \
    TAILR(acc, cst, hv, 2); TAILR(acc, cst, hv, 3);                                    \
    *(bf16x4*)&hbuf[wb][c * HSTR + w * 16 + q * 4] = hv; /* h(T) */                    \
    asm volatile("s_waitcnt lgkmcnt(0)" ::: "memory");                                 \
    if (lane == 0) ((volatile unsigned short*)hfl)[w] = (unsigned short)((T) + 1);     \
  } while (0)

#define RUN(KA, KB, KC, KD)                                                            \
  do {                                                                                 \
    ITER_K(hfB, hfA, 2, false, KA, KB, KC, KD);                                        \
    for (int p = 0; p < 255; ++p) {                                                    \
      ITER_K(hfA, hfB, 3 + 2 * p, true, KA, KB, KC, KD);                               \
      ITER_K(hfB, hfA, 4 + 2 * p, true, KA, KB, KC, KD);                               \
    }                                                                                  \
  } while (0)

  const int k0 = w >> 1;  // own pair first; SIMD-mates differ by 2 (opposite halves)
  if (k0 == 0)      RUN(0, 1, 2, 3);
  else if (k0 == 1) RUN(1, 2, 3, 0);
  else if (k0 == 2) RUN(2, 3, 0, 1);
  else              RUN(3, 0, 1, 2);

  // epilogue: y(h(511)) from hfB (row 510); then read h(512) (buf 0) and emit (row 511)
  if (w < 5) {
    YEMIT(hfB);
    POLLP(0, 513); POLLP(1, 513); POLLP(2, 513); POLLP(3, 513);
#pragma unroll
    for (int kt = 0; kt < 4; ++kt)
      hfA[kt] = *(const bf16x8*)&hbuf[0][c * HSTR + kt * 32 + q * 8];
    YEMIT(hfA);
  }
#undef RUN
#undef ITER_K
}

extern "C" void kernel_launch(void* const* d_in, const int* in_sizes, int n_in,
                              void* d_out, int out_size, void* d_ws, size_t ws_size,
                              hipStream_t stream) {
  const float* h0   = (const float*)d_in[0];
  const float* W_ih = (const float*)d_in[1];
  const float* W_hh = (const float*)d_in[2];
  const float* b_ih = (const float*)d_in[3];
  const float* b_hh = (const float*)d_in[4];
  const float* W_fc = (const float*)d_in[5];
  const float* b_fc = (const float*)d_in[6];
  float* out = (float*)d_out;

  k_weff<<<256, 256, 0, stream>>>(W_ih, W_hh, b_ih, b_hh, W_fc, b_fc);
  k_frag<<<276, 64, 0, stream>>>(W_hh, W_fc);
  k_lstm<<<NBLK, 512, 0, stream>>>(h0, b_fc, out);
}